// Round 1
// baseline (212.631 us; speedup 1.0000x reference)
//
#include <hip/hip_runtime.h>
#include <hip/hip_cooperative_groups.h>

namespace cg = cooperative_groups;

// SystemIDModel: y[k] = poly8(x2[k]) - x1[k] - R0*u[k]
//   x1[k] = A00*x1[k-1] + B0*u[k-1]   (x1[0]=0)   A00 = exp(-dt/(Rp*Cp)), B0 = Rp*(1-A00)
//   x2[k] = x2[k-1] + B1*u[k-1]       (x2[0]=1)   B1 = -1/5400
//
// FUSED single-dispatch cooperative scan (was: 2 dispatches, u read twice).
//   Phase 1: load u into registers, per-thread serial scan, wave shuffle scan,
//            publish per-chunk aggregates (agent-scope atomic stores).
//   grid.sync()
//   Phase 2: block-parallel redundant carry reduce of aggP[0..b), carryW from
//            aggW[b-1] (A00^CHUNK underflows to 0 for these inputs; general
//            fallback retained), assemble prefixes, emit — all from registers.
// u is read exactly once (16 MB), out written once (16 MB).

constexpr int BLOCK = 256;
constexpr int TPER  = 16;
constexpr int CHUNK = BLOCK * TPER;    // 4096
constexpr int NTOT  = 4194304;
constexpr int NB    = NTOT / CHUNK;    // 1024 blocks = 4/CU * 256 CU -> co-resident
constexpr int WPB   = BLOCK / 64;      // 4 waves per block
constexpr int APT   = NB / BLOCK;      // aggP entries per thread in reduce = 4

__global__ __launch_bounds__(BLOCK, 4) void k_fused(
    const float* __restrict__ u,
    const float* __restrict__ Rp_p, const float* __restrict__ Cp_p,
    const float* __restrict__ R0_p, const float* __restrict__ ac,
    float* __restrict__ aggW, float* __restrict__ aggP,
    float* __restrict__ out)
{
    __shared__ float LW[WPB], LP[WPB];
    __shared__ float sRed[WPB];
    __shared__ float sCW;

    const int b = blockIdx.x, t = threadIdx.x;
    const int lane = t & 63, w = t >> 6;

    const float Rp  = Rp_p[0];
    const float invRC = 1.0f / (Rp * Cp_p[0]);
    const float A00 = __expf(-invRC);
    const float B0  = Rp * (1.0f - A00);
    const float B1  = -1.0f / 5400.0f;                   // -eta*dt/(1.5*3600)
    const float a2 = A00 * A00, a4 = a2 * a2, a8 = a4 * a4;
    const float f16 = a8 * a8;                           // A00^TPER
    float f1024 = f16;
    for (int i = 0; i < 6; ++i) f1024 *= f1024;          // A00^1024 (0.0f here)
    const float dC = (f1024 * f1024) * (f1024 * f1024);  // A00^CHUNK (0.0f here)

    // ---- Phase 1: load chunk (the ONLY read of u), thread scan, wave scan ----
    const size_t base = (size_t)b * CHUNK + (size_t)t * TPER;
    const float4* up = (const float4*)(u + base);
    float4 v[4];
    v[0] = up[0]; v[1] = up[1]; v[2] = up[2]; v[3] = up[3];
    const float* uu = (const float*)v;

    float s = 0.0f, p = 0.0f;
#pragma unroll
    for (int i = 0; i < TPER; ++i) { s = fmaf(A00, s, uu[i]); p += uu[i]; }

    float fk = f16;
#pragma unroll
    for (int k = 1; k < 64; k <<= 1) {
        const float sw = __shfl_up(s, k, 64);
        const float pw = __shfl_up(p, k, 64);
        if (lane >= k) { s = fmaf(sw, fk, s); p += pw; }
        fk *= fk;
    }
    if (lane == 63) { LW[w] = s; LP[w] = p; }
    __syncthreads();

    if (t == 0) {
        float W = LW[0], P = LP[0];
        for (int q = 1; q < WPB; ++q) { W = fmaf(W, f1024, LW[q]); P += LP[q]; }
        // agent-scope stores: visible across XCDs after grid sync
        __hip_atomic_store(&aggW[b], W, __ATOMIC_RELAXED, __HIP_MEMORY_SCOPE_AGENT);
        __hip_atomic_store(&aggP[b], P, __ATOMIC_RELAXED, __HIP_MEMORY_SCOPE_AGENT);
    }

    cg::this_grid().sync();

    // ---- Phase 2a: carryP partial — block-parallel masked reduce of aggP[0..b) ----
    float pc = 0.0f;
#pragma unroll
    for (int i = 0; i < APT; ++i) {
        const int j = t * APT + i;
        if (j < b)
            pc += __hip_atomic_load(&aggP[j], __ATOMIC_RELAXED, __HIP_MEMORY_SCOPE_AGENT);
    }
#pragma unroll
    for (int off = 32; off; off >>= 1) pc += __shfl_down(pc, off, 64);
    if (lane == 0) sRed[w] = pc;

    // ---- carryW (block) ----
    if (t == 0) {
        float cW;
        if (dC == 0.0f) {
            cW = (b > 0) ? __hip_atomic_load(&aggW[b - 1], __ATOMIC_RELAXED,
                                             __HIP_MEMORY_SCOPE_AGENT)
                         : 0.0f;
        } else {                                         // general fallback
            cW = 0.0f;
            for (int j = 0; j < b; ++j)
                cW = fmaf(cW, dC, __hip_atomic_load(&aggW[j], __ATOMIC_RELAXED,
                                                    __HIP_MEMORY_SCOPE_AGENT));
        }
        sCW = cW;
    }
    __syncthreads();

    // ---- Phase 2b: assemble per-thread exclusive prefixes (reuse s, p, LW, LP) ----
    float carryP_blk = 0.0f;
#pragma unroll
    for (int q = 0; q < WPB; ++q) carryP_blk += sRed[q];

    float cw = 0.0f, cp = 0.0f;                          // previous-wave carries
    for (int q = 0; q < w; ++q) { cw = fmaf(cw, f1024, LW[q]); cp += LP[q]; }

    float fw = 1.0f;                                     // f1024^w
    for (int q = 0; q < w; ++q) fw *= f1024;

    float fl = 1.0f, bse = f16;                          // f16^lane (square-multiply)
#pragma unroll
    for (int k = 0; k < 6; ++k) { if (lane & (1 << k)) fl *= bse; bse *= bse; }

    const float upW = __shfl_up(s, 1, 64);
    const float upP = __shfl_up(p, 1, 64);
    float Wcur = (lane ? upW : 0.0f) + fmaf(sCW, fw, cw) * fl;  // W at elem base
    float Pcur = (lane ? upP : 0.0f) + cp + carryP_blk;         // P at elem base

    // ---- emit 16 outputs/thread ----
    const float R0f = R0_p[0];
    float af[9];
#pragma unroll
    for (int i = 0; i < 9; ++i) af[i] = ac[i];

    float4 o[4];
    float* oy = (float*)o;
#pragma unroll
    for (int i = 0; i < TPER; ++i) {
        const float x2 = fmaf(B1, Pcur, 1.0f);           // INITIAL_X2 = 1
        float poly = af[8];
#pragma unroll
        for (int j = 7; j >= 0; --j) poly = fmaf(poly, x2, af[j]);
        oy[i] = poly - B0 * Wcur - R0f * uu[i];
        Wcur = fmaf(A00, Wcur, uu[i]);                   // emit state BEFORE update
        Pcur += uu[i];
    }
    float4* op = (float4*)(out + base);
    op[0] = o[0]; op[1] = o[1]; op[2] = o[2]; op[3] = o[3];
}

// ---------------- Fallback path: original 2-dispatch structure ----------------
__global__ __launch_bounds__(BLOCK) void kA_agg(
    const float* __restrict__ u,
    const float* __restrict__ Rp_p, const float* __restrict__ Cp_p,
    float* __restrict__ aggW, float* __restrict__ aggP)
{
    __shared__ float LW[WPB], LP[WPB];
    const int b = blockIdx.x, t = threadIdx.x;
    const int lane = t & 63, w = t >> 6;

    const float invRC = 1.0f / (Rp_p[0] * Cp_p[0]);
    const float A00 = __expf(-invRC);
    const float a2 = A00 * A00, a4 = a2 * a2, a8 = a4 * a4;
    const float f16 = a8 * a8;

    const float4* up = (const float4*)(u + (size_t)b * CHUNK + (size_t)t * TPER);
    float4 v[4];
    v[0] = up[0]; v[1] = up[1]; v[2] = up[2]; v[3] = up[3];
    const float* uu = (const float*)v;

    float s = 0.0f, p = 0.0f;
#pragma unroll
    for (int i = 0; i < TPER; ++i) { s = fmaf(A00, s, uu[i]); p += uu[i]; }

    float fk = f16;
#pragma unroll
    for (int k = 1; k < 64; k <<= 1) {
        const float sw = __shfl_up(s, k, 64);
        const float pw = __shfl_up(p, k, 64);
        if (lane >= k) { s = fmaf(sw, fk, s); p += pw; }
        fk *= fk;
    }
    if (lane == 63) { LW[w] = s; LP[w] = p; }
    __syncthreads();

    if (t == 0) {
        float f1024 = f16;
        for (int i = 0; i < 6; ++i) f1024 *= f1024;
        float W = LW[0], P = LP[0];
        for (int q = 1; q < WPB; ++q) { W = fmaf(W, f1024, LW[q]); P += LP[q]; }
        aggW[b] = W; aggP[b] = P;
    }
}

__global__ __launch_bounds__(BLOCK) void kB_emit(
    const float* __restrict__ u,
    const float* __restrict__ Rp_p, const float* __restrict__ Cp_p,
    const float* __restrict__ R0_p, const float* __restrict__ ac,
    const float* __restrict__ aggW, const float* __restrict__ aggP,
    float* __restrict__ out)
{
    __shared__ float LW[WPB], LP[WPB];
    __shared__ float sRed[WPB];
    __shared__ float sCW;

    const int b = blockIdx.x, t = threadIdx.x;
    const int lane = t & 63, w = t >> 6;

    const float invRC = 1.0f / (Rp_p[0] * Cp_p[0]);
    const float A00 = __expf(-invRC);
    const float B0  = Rp_p[0] * (1.0f - A00);
    const float B1  = -1.0f / 5400.0f;
    const float R0f = R0_p[0];
    const float a2 = A00 * A00, a4 = a2 * a2, a8 = a4 * a4;
    const float f16 = a8 * a8;
    float f1024 = f16;
    for (int i = 0; i < 6; ++i) f1024 *= f1024;
    const float dC = (f1024 * f1024) * (f1024 * f1024);

    const size_t base = (size_t)b * CHUNK + (size_t)t * TPER;
    const float4* up = (const float4*)(u + base);
    float4 v[4];
    v[0] = up[0]; v[1] = up[1]; v[2] = up[2]; v[3] = up[3];
    const float* uu = (const float*)v;

    float pc = 0.0f;
#pragma unroll
    for (int i = 0; i < APT; ++i) {
        const int j = t * APT + i;
        if (j < b) pc += aggP[j];
    }
#pragma unroll
    for (int off = 32; off; off >>= 1) pc += __shfl_down(pc, off, 64);
    if (lane == 0) sRed[w] = pc;

    if (t == 0) {
        float cW;
        if (dC == 0.0f) {
            cW = (b > 0) ? aggW[b - 1] : 0.0f;
        } else {
            cW = 0.0f;
            for (int j = 0; j < b; ++j) cW = fmaf(cW, dC, aggW[j]);
        }
        sCW = cW;
    }

    float s = 0.0f, p = 0.0f;
#pragma unroll
    for (int i = 0; i < TPER; ++i) { s = fmaf(A00, s, uu[i]); p += uu[i]; }
    float fk = f16;
#pragma unroll
    for (int k = 1; k < 64; k <<= 1) {
        const float sw = __shfl_up(s, k, 64);
        const float pw = __shfl_up(p, k, 64);
        if (lane >= k) { s = fmaf(sw, fk, s); p += pw; }
        fk *= fk;
    }
    if (lane == 63) { LW[w] = s; LP[w] = p; }
    __syncthreads();

    float carryP_blk = 0.0f;
#pragma unroll
    for (int q = 0; q < WPB; ++q) carryP_blk += sRed[q];

    float cw = 0.0f, cp = 0.0f;
    for (int q = 0; q < w; ++q) { cw = fmaf(cw, f1024, LW[q]); cp += LP[q]; }

    float fw = 1.0f;
    for (int q = 0; q < w; ++q) fw *= f1024;

    float fl = 1.0f, bse = f16;
#pragma unroll
    for (int k = 0; k < 6; ++k) { if (lane & (1 << k)) fl *= bse; bse *= bse; }

    const float upW = __shfl_up(s, 1, 64);
    const float upP = __shfl_up(p, 1, 64);
    float Wcur = (lane ? upW : 0.0f) + fmaf(sCW, fw, cw) * fl;
    float Pcur = (lane ? upP : 0.0f) + cp + carryP_blk;

    float af[9];
#pragma unroll
    for (int i = 0; i < 9; ++i) af[i] = ac[i];

    float4 o[4];
    float* oy = (float*)o;
#pragma unroll
    for (int i = 0; i < TPER; ++i) {
        const float x2 = fmaf(B1, Pcur, 1.0f);
        float poly = af[8];
#pragma unroll
        for (int j = 7; j >= 0; --j) poly = fmaf(poly, x2, af[j]);
        oy[i] = poly - B0 * Wcur - R0f * uu[i];
        Wcur = fmaf(A00, Wcur, uu[i]);
        Pcur += uu[i];
    }
    float4* op = (float4*)(out + base);
    op[0] = o[0]; op[1] = o[1]; op[2] = o[2]; op[3] = o[3];
}

extern "C" void kernel_launch(void* const* d_in, const int* in_sizes, int n_in,
                              void* d_out, int out_size, void* d_ws, size_t ws_size,
                              hipStream_t stream) {
    const float* u    = (const float*)d_in[0];
    const float* Rp_p = (const float*)d_in[1];
    const float* Cp_p = (const float*)d_in[2];
    const float* R0_p = (const float*)d_in[3];
    const float* ac   = (const float*)d_in[4];
    float* out = (float*)d_out;

    float* wsW = (float*)d_ws;        // [NB]
    float* wsP = (float*)d_ws + NB;   // [NB]

    void* args[] = {(void*)&u, (void*)&Rp_p, (void*)&Cp_p, (void*)&R0_p,
                    (void*)&ac, (void*)&wsW, (void*)&wsP, (void*)&out};
    hipError_t err = hipLaunchCooperativeKernel((const void*)k_fused, dim3(NB),
                                                dim3(BLOCK), args, 0, stream);
    if (err != hipSuccess) {
        // Fallback: original verified 2-dispatch path
        kA_agg <<<NB, BLOCK, 0, stream>>>(u, Rp_p, Cp_p, wsW, wsP);
        kB_emit<<<NB, BLOCK, 0, stream>>>(u, Rp_p, Cp_p, R0_p, ac, wsW, wsP, out);
    }
}